// Round 6
// baseline (163.408 us; speedup 1.0000x reference)
//
#include <hip/hip_runtime.h>

#define B_N   8
#define S_LEN 2048
#define D_DIM 256

typedef __attribute__((ext_vector_type(4)))  float          f32x4;
typedef __attribute__((ext_vector_type(16))) float          f32x16;
typedef __attribute__((ext_vector_type(8)))  short          s16x8;
typedef __attribute__((ext_vector_type(8)))  __bf16         b16x8;
typedef __attribute__((ext_vector_type(8)))  unsigned short u16x8;
typedef __attribute__((ext_vector_type(4)))  unsigned int   u32x4;

// ---- bf16 helpers (RNE) ----
__device__ __forceinline__ unsigned short f2bf(float f) {
    unsigned u = __builtin_bit_cast(unsigned, f);
    u += 0x7FFFu + ((u >> 16) & 1u);
    return (unsigned short)(u >> 16);
}
__device__ __forceinline__ u16x8 pack8(f32x4 a, f32x4 b) {
    u16x8 o;
#pragma unroll
    for (int u = 0; u < 4; ++u) { o[u] = f2bf(a[u]); o[u + 4] = f2bf(b[u]); }
    return o;
}
__device__ __forceinline__ f32x16 zero16() {
    f32x16 z;
#pragma unroll
    for (int i = 0; i < 16; ++i) z[i] = 0.f;
    return z;
}
// packed f32->bf16 pair (HW RNE), no builtin on gfx950 -> asm
__device__ __forceinline__ unsigned cvtpk(float lo, float hi) {
    unsigned r;
    asm("v_cvt_pk_bf16_f32 %0, %1, %2" : "=v"(r) : "v"(lo), "v"(hi));
    return r;
}
// exchange (lane l: y) <-> (lane l+32: x)
__device__ __forceinline__ void xswap(unsigned& x, unsigned& y, int lh) {
    unsigned vs = lh ? x : y;
    unsigned vr = (unsigned)__shfl_xor((int)vs, 32, 64);
    x = lh ? vr : x;
    y = lh ? y : vr;
}
// raw HW transcendentals (VOP1): ~1 ulp
__device__ __forceinline__ float hw_sqrt(float x) {
    float r; asm("v_sqrt_f32 %0, %1" : "=v"(r) : "v"(x)); return r;
}
__device__ __forceinline__ float hw_log2(float x) {
    float r; asm("v_log_f32 %0, %1" : "=v"(r) : "v"(x)); return r;
}
__device__ __forceinline__ float hw_exp2(float x) {
    float r; asm("v_exp_f32 %0, %1" : "=v"(r) : "v"(x)); return r;
}
__device__ __forceinline__ float hw_rcp(float x) {
    float r; asm("v_rcp_f32 %0, %1" : "=v"(r) : "v"(x)); return r;
}
// async global->LDS, 16B per lane, dest = wave-uniform base + lane*16 (linear)
__device__ __forceinline__ void gload16(const void* g, void* l) {
    __builtin_amdgcn_global_load_lds((const __attribute__((address_space(1))) void*)g,
                                     (__attribute__((address_space(3))) void*)l, 16, 0, 0);
}

// ---- MFMA wrapper: tolerate either short8 or bf16x8 builtin signature ----
template <typename A>
__device__ __forceinline__ auto mfma3216_(A a, A b, f32x16 c, int)
    -> decltype(__builtin_amdgcn_mfma_f32_32x32x16_bf16(a, b, c, 0, 0, 0)) {
    return __builtin_amdgcn_mfma_f32_32x32x16_bf16(a, b, c, 0, 0, 0);
}
template <typename A>
__device__ __forceinline__ f32x16 mfma3216_(A a, A b, f32x16 c, long) {
    b16x8 a2 = __builtin_bit_cast(b16x8, a);
    b16x8 b2 = __builtin_bit_cast(b16x8, b);
    return __builtin_amdgcn_mfma_f32_32x32x16_bf16(a2, b2, c, 0, 0, 0);
}
__device__ __forceinline__ f32x16 MFMA(u16x8 a, u16x8 b, f32x16 c) {
    return mfma3216_(__builtin_bit_cast(s16x8, a), __builtin_bit_cast(s16x8, b), c, 0);
}

// ================= P0: per-row stats (fp32, faithful to reference) =================
__global__ void __launch_bounds__(256) prep_rows(const float* __restrict__ Q,
                                                 const float* __restrict__ K,
                                                 const float* __restrict__ cp,
                                                 float* __restrict__ q2g,
                                                 float* __restrict__ k2g,
                                                 float* __restrict__ cfg) {
    const int w = threadIdx.x >> 6, l = threadIdx.x & 63;
    const float c = *cp;
#pragma unroll 1
    for (int p = 0; p < 16; ++p) {
        const int row = blockIdx.x * 64 + p * 4 + w;
        f32x4 qv = *((const f32x4*)(Q + (size_t)row * D_DIM) + l);
        f32x4 kv = *((const f32x4*)(K + (size_t)row * D_DIM) + l);
        float sq = qv[0]*qv[0] + qv[1]*qv[1] + qv[2]*qv[2] + qv[3]*qv[3];
        float sk = kv[0]*kv[0] + kv[1]*kv[1] + kv[2]*kv[2] + kv[3]*kv[3];
#pragma unroll
        for (int m = 1; m < 64; m <<= 1) {
            sq += __shfl_xor(sq, m, 64);
            sk += __shfl_xor(sk, m, 64);
        }
        if (l == 0) {
            q2g[row] = sq;
            k2g[row] = sk;
            float dn = fmaxf((1.f - c * sq) * (1.f - c * sk), 1e-6f);
            cfg[row] = 2.f * c / dn;
        }
    }
}

// ================= P1a: K -> bf16 =================
__global__ void __launch_bounds__(256) cvt_bf16(const float* __restrict__ src,
                                                unsigned short* __restrict__ dst) {
    const size_t i = ((size_t)blockIdx.x * 256 + threadIdx.x) * 8;
    f32x4 a = *(const f32x4*)(src + i);
    f32x4 b = *(const f32x4*)(src + i + 4);
    *(u16x8*)(dst + i) = pack8(a, b);
}

// ================= P1b: V -> bf16, transposed per batch: VT[b][d][j] =================
__global__ void __launch_bounds__(256) transp_v(const float* __restrict__ V,
                                                unsigned short* __restrict__ VT) {
    __shared__ float tile[64][65];
    const int bid = blockIdx.x;
    const int b = bid >> 7, rem = bid & 127, jt = rem >> 2, dt = rem & 3;
    const int j0 = jt * 64, d0 = dt * 64;
    const int t = threadIdx.x;
#pragma unroll
    for (int p = 0; p < 4; ++p) {
        const int jr = p * 16 + (t >> 4);
        f32x4 v = *(const f32x4*)(V + (size_t)(b * S_LEN + j0 + jr) * D_DIM + d0 + (t & 15) * 4);
#pragma unroll
        for (int u = 0; u < 4; ++u) tile[jr][(t & 15) * 4 + u] = v[u];
    }
    __syncthreads();
#pragma unroll
    for (int p = 0; p < 2; ++p) {
        const int dr = p * 32 + (t >> 3), seg = t & 7;
        u16x8 o;
#pragma unroll
        for (int u = 0; u < 8; ++u) o[u] = f2bf(tile[seg * 8 + u][dr]);
        *(u16x8*)(VT + (size_t)(b * D_DIM + d0 + dr) * S_LEN + j0 + seg * 8) = o;
    }
}

// ================= Main fused attention =================
// grid 256 = batch(8, ==XCD) x qtile(32, 64 q-rows)  [r4's proven mapping].
// block 256 (4 waves) = qg(2, 32 q-rows) x jsub(2).  Each block contracts ALL
// 2048 j in-block (32 iters x 64-j tiles) -> no cross-block normalize race.
// LDS 74.2KB -> 2 blocks/CU co-resident: cross-block overlap hides the
// stage-drain barriers (replaces explicit double buffering).
// Swapped QK^T + in-register P transpose (validated r3/r4). p=y^(-1/16)<=1:
// no online max needed. K rows 512B / VT rows 128B, XOR slot swizzle (row&7).
template <int PRE>
__global__ void __launch_bounds__(256, 2) hyp_attn(
    const float* __restrict__ Qf, const float* __restrict__ Kf, const float* __restrict__ Vf,
    const unsigned short* __restrict__ Kb, const unsigned short* __restrict__ VTg,
    const float* __restrict__ q2g, const float* __restrict__ k2g, const float* __restrict__ cfg,
    float* __restrict__ out) {
    // K tile @0 (32KB: 64 rows x 512B) | VT tile @32768 (32KB: 256 d x 128B)
    __shared__ __align__(1024) unsigned char tiles[65536];
    __shared__ float k2sh[S_LEN];        // 8192 B (full batch row)
    __shared__ float lsumBuf[2][2][32];  // 512 B    => 74240 B total

    const int bid = blockIdx.x;
    const int nb = (bid & 7) * 32 + (bid >> 3);  // batch == XCD
    const int b = nb >> 5, rt = nb & 31;
    const int tid = threadIdx.x;
    const int w = tid >> 6, l = tid & 63;
    const int l31 = l & 31, lh = l >> 5;
    const int qg = w >> 1, jsub = w & 1;
    const int qr0 = rt * 64 + qg * 32;
    const int qrow = b * S_LEN + qr0 + l31;

    // stage the batch's k2 row once (visible after first loop barrier)
    *(f32x4*)&k2sh[tid * 8]     = *(const f32x4*)(k2g + b * S_LEN + tid * 8);
    *(f32x4*)&k2sh[tid * 8 + 4] = *(const f32x4*)(k2g + b * S_LEN + tid * 8 + 4);

    // ---- Q fragments (B-operand: col=l31, k=lh*8+j), fp32->bf16 once ----
    u16x8 qf[16];
    {
        const float* qp = Qf + (size_t)qrow * D_DIM + lh * 8;
#pragma unroll
        for (int ks = 0; ks < 16; ++ks) {
            f32x4 a = *(const f32x4*)(qp + ks * 16);
            f32x4 c4 = *(const f32x4*)(qp + ks * 16 + 4);
            qf[ks] = pack8(a, c4);
        }
    }
    const float q2r = q2g[qrow];
    const float cfr = cfg[qrow];
    const float base1 = fmaf(cfr, q2r, 1.0f);  // 1 + cf*q2

    f32x16 oacc[8];
#pragma unroll
    for (int i = 0; i < 8; ++i) oacc[i] = zero16();
    float lsum = 0.f;

    const size_t kbBase = (size_t)b * S_LEN * D_DIM;

    auto stage = [&](int it) {
        const int j0 = it * 64;
        if (PRE) {
#pragma unroll
            for (int p = 0; p < 8; ++p) {  // K: 64 rows x 32 slots(16B)
                const int idx = p * 256 + tid;
                const int row = idx >> 5, sl = idx & 31;
                const unsigned short* gp = Kb + kbBase + (size_t)(j0 + row) * D_DIM
                                         + ((sl ^ (row & 7)) << 3);
                gload16(gp, (char*)tiles + idx * 16);
            }
#pragma unroll
            for (int p = 0; p < 8; ++p) {  // VT: 256 d x 8 slots(16B)
                const int idx = p * 256 + tid;
                const int d = idx >> 3, sl = idx & 7;
                const unsigned short* gp = VTg + ((size_t)b * D_DIM + d) * S_LEN + j0
                                         + ((sl ^ (d & 7)) << 3);
                gload16(gp, (char*)tiles + 32768 + idx * 16);
            }
        } else {
#pragma unroll
            for (int p = 0; p < 8; ++p) {  // K from fp32 (reg-staged)
                const int idx = p * 256 + tid;
                const int row = idx >> 5, sl = idx & 31;
                const float* sp = Kf + kbBase + (size_t)(j0 + row) * D_DIM
                                + ((sl ^ (row & 7)) << 3);
                *(u16x8*)((char*)tiles + idx * 16) =
                    pack8(*(const f32x4*)sp, *(const f32x4*)(sp + 4));
            }
#pragma unroll
            for (int p = 0; p < 8; ++p) {  // V gather-transpose (slow fallback)
                const int idx = p * 256 + tid;
                const int d = idx >> 3, sl = idx & 7;
                const int jj = (sl ^ (d & 7)) << 3;
                u16x8 o;
#pragma unroll
                for (int u = 0; u < 8; ++u)
                    o[u] = f2bf(Vf[kbBase + (size_t)(j0 + jj + u) * D_DIM + d]);
                *(u16x8*)((char*)tiles + 32768 + idx * 16) = o;
            }
        }
    };

    const int xk = (l31 & 7) << 4;
    const char* KBp = (const char*)tiles + (jsub * 32 + l31) * 512;
    const char* VBp = (const char*)tiles + 32768 + l31 * 128;

#pragma unroll 1
    for (int it = 0; it < 32; ++it) {
        stage(it);
        __syncthreads();  // drains staging (vmcnt0) -> tiles valid

        // ---- swapped QK^T: sacc[r] = S[j=jsub*32+crow(r,lh)][q=l31] ----
        f32x16 sacc = zero16();
#pragma unroll
        for (int ks = 0; ks < 16; ++ks) {
            u16x8 kf = *(const u16x8*)(KBp + (((ks * 2 + lh) << 4) ^ xk));
            sacc = MFMA(kf, qf[ks], sacc);
        }

        // ---- k2 for this wave's 32 j-rows (broadcast b128 reads) ----
        f32x4 k2q[4];
#pragma unroll
        for (int g = 0; g < 4; ++g)
            k2q[g] = *(const f32x4*)&k2sh[it * 64 + jsub * 32 + g * 8 + lh * 4];

        // ---- hyperbolic logits -> p (in place) ----
#pragma unroll
        for (int r = 0; r < 16; ++r) {
            const float t = fmaf(-2.f, sacc[r], k2q[r >> 2][r & 3]);  // k2 - 2S
            const float arg = fmaxf(fmaf(cfr, t, base1), 1.f + 1e-6f);
            const float y = arg + hw_sqrt(fmaf(arg, arg, -1.f));      // e^{arccosh}
            const float p = hw_exp2(hw_log2(y) * -0.0625f);           // y^(-1/16)
            lsum += p;
            sacc[r] = p;
        }

        // ---- in-register P transpose: lane gets A-frag rows (q=l31) ----
        unsigned A_ = cvtpk(sacc[0], sacc[1]),   C_ = cvtpk(sacc[2], sacc[3]);
        unsigned Bv = cvtpk(sacc[4], sacc[5]),   D_ = cvtpk(sacc[6], sacc[7]);
        unsigned E_ = cvtpk(sacc[8], sacc[9]),   G_ = cvtpk(sacc[10], sacc[11]);
        unsigned F_ = cvtpk(sacc[12], sacc[13]), H_ = cvtpk(sacc[14], sacc[15]);
        xswap(A_, Bv, lh); xswap(C_, D_, lh);
        xswap(E_, F_, lh); xswap(G_, H_, lh);
        const u16x8 pa0 = __builtin_bit_cast(u16x8, (u32x4){A_, C_, Bv, D_});
        const u16x8 pa1 = __builtin_bit_cast(u16x8, (u32x4){E_, G_, F_, H_});

        // ---- PV: O += P * V ----
#pragma unroll
        for (int db = 0; db < 8; ++db) {
            u16x8 vf0 = *(const u16x8*)(VBp + db * 4096 +
                                        (((jsub * 4 + lh) << 4) ^ xk));
            oacc[db] = MFMA(pa0, vf0, oacc[db]);
            u16x8 vf1 = *(const u16x8*)(VBp + db * 4096 +
                                        (((jsub * 4 + 2 + lh) << 4) ^ xk));
            oacc[db] = MFMA(pa1, vf1, oacc[db]);
        }
        __syncthreads();  // all reads of this tile done before next overwrite
    }

    // ---- epilogue: combine jsub partials (2-way) ----
    lsum += __shfl_xor(lsum, 32, 64);  // join lh halves: per-q total (this jsub)
    if (lh == 0) lsumBuf[jsub][qg][l31] = lsum;
    float* sf = (float*)tiles;  // 2 qg x 32 q x 256 d fp32 = 64KB
    if (jsub == 1) {
#pragma unroll
        for (int db = 0; db < 8; ++db)
#pragma unroll
            for (int r = 0; r < 16; ++r) {
                const int crow = (r & 3) + 8 * (r >> 2) + 4 * lh;
                sf[qg * 8192 + crow * 256 + db * 32 + l31] = oacc[db][r];
            }
    }
    __syncthreads();
    if (jsub == 0) {
        float rdn[16];
#pragma unroll
        for (int r = 0; r < 16; ++r) {
            const int crow = (r & 3) + 8 * (r >> 2) + 4 * lh;
            rdn[r] = hw_rcp(lsumBuf[0][qg][crow] + lsumBuf[1][qg][crow]);
        }
#pragma unroll
        for (int db = 0; db < 8; ++db)
#pragma unroll
            for (int r = 0; r < 16; ++r) {
                const int crow = (r & 3) + 8 * (r >> 2) + 4 * lh;
                const float o = oacc[db][r] + sf[qg * 8192 + crow * 256 + db * 32 + l31];
                out[(size_t)(b * S_LEN + qr0 + crow) * D_DIM + db * 32 + l31] = o * rdn[r];
            }
    }
}

// ================= launcher =================
extern "C" void kernel_launch(void* const* d_in, const int* in_sizes, int n_in,
                              void* d_out, int out_size, void* d_ws, size_t ws_size,
                              hipStream_t stream) {
    const float* Q = (const float*)d_in[0];
    const float* K = (const float*)d_in[1];
    const float* V = (const float*)d_in[2];
    const float* cp = (const float*)d_in[3];
    float* out = (float*)d_out;
    (void)in_sizes; (void)n_in; (void)out_size;

    const size_t BS = (size_t)B_N * S_LEN;
    float* q2g = (float*)d_ws;
    float* k2g = q2g + BS;
    float* cfg = k2g + BS;
    unsigned short* Kb = (unsigned short*)(cfg + BS);
    unsigned short* VTg = Kb + BS * D_DIM;
    const size_t need_full = 3 * BS * 4 + 2 * BS * D_DIM * 2;  // ~17 MB

    prep_rows<<<(B_N * S_LEN) / 64, 256, 0, stream>>>(Q, K, cp, q2g, k2g, cfg);

    if (ws_size >= need_full) {
        cvt_bf16<<<(int)((BS * D_DIM / 8) / 256), 256, 0, stream>>>(K, Kb);
        transp_v<<<B_N * (S_LEN / 64) * (D_DIM / 64), 256, 0, stream>>>(V, VTg);
        hyp_attn<1><<<256, 256, 0, stream>>>(Q, K, V, Kb, VTg, q2g, k2g, cfg, out);
    } else {
        hyp_attn<0><<<256, 256, 0, stream>>>(Q, K, V, Kb, VTg, q2g, k2g, cfg, out);
    }
}

// Round 7
// 103.862 us; speedup vs baseline: 1.5733x; 1.5733x over previous
//
#include <hip/hip_runtime.h>

#define B_N   8
#define S_LEN 2048
#define D_DIM 256

typedef __attribute__((ext_vector_type(4)))  float          f32x4;
typedef __attribute__((ext_vector_type(16))) float          f32x16;
typedef __attribute__((ext_vector_type(8)))  short          s16x8;
typedef __attribute__((ext_vector_type(8)))  __bf16         b16x8;
typedef __attribute__((ext_vector_type(8)))  unsigned short u16x8;
typedef __attribute__((ext_vector_type(4)))  unsigned int   u32x4;

// ---- bf16 helpers (RNE) ----
__device__ __forceinline__ unsigned short f2bf(float f) {
    unsigned u = __builtin_bit_cast(unsigned, f);
    u += 0x7FFFu + ((u >> 16) & 1u);
    return (unsigned short)(u >> 16);
}
__device__ __forceinline__ u16x8 pack8(f32x4 a, f32x4 b) {
    u16x8 o;
#pragma unroll
    for (int u = 0; u < 4; ++u) { o[u] = f2bf(a[u]); o[u + 4] = f2bf(b[u]); }
    return o;
}
__device__ __forceinline__ f32x16 zero16() {
    f32x16 z;
#pragma unroll
    for (int i = 0; i < 16; ++i) z[i] = 0.f;
    return z;
}
// packed f32->bf16 pair (HW RNE), no builtin on gfx950 -> asm
__device__ __forceinline__ unsigned cvtpk(float lo, float hi) {
    unsigned r;
    asm("v_cvt_pk_bf16_f32 %0, %1, %2" : "=v"(r) : "v"(lo), "v"(hi));
    return r;
}
// exchange (lane l: y) <-> (lane l+32: x)
__device__ __forceinline__ void xswap(unsigned& x, unsigned& y, int lh) {
    unsigned vs = lh ? x : y;
    unsigned vr = (unsigned)__shfl_xor((int)vs, 32, 64);
    x = lh ? vr : x;
    y = lh ? y : vr;
}
// raw HW transcendentals (VOP1): ~1 ulp
__device__ __forceinline__ float hw_sqrt(float x) {
    float r; asm("v_sqrt_f32 %0, %1" : "=v"(r) : "v"(x)); return r;
}
__device__ __forceinline__ float hw_log2(float x) {
    float r; asm("v_log_f32 %0, %1" : "=v"(r) : "v"(x)); return r;
}
__device__ __forceinline__ float hw_exp2(float x) {
    float r; asm("v_exp_f32 %0, %1" : "=v"(r) : "v"(x)); return r;
}
__device__ __forceinline__ float hw_rcp(float x) {
    float r; asm("v_rcp_f32 %0, %1" : "=v"(r) : "v"(x)); return r;
}
// async global->LDS, 16B per lane, dest = wave-uniform base + lane*16 (linear)
__device__ __forceinline__ void gload16(const void* g, void* l) {
    __builtin_amdgcn_global_load_lds((const __attribute__((address_space(1))) void*)g,
                                     (__attribute__((address_space(3))) void*)l, 16, 0, 0);
}

// ---- MFMA wrapper: tolerate either short8 or bf16x8 builtin signature ----
template <typename A>
__device__ __forceinline__ auto mfma3216_(A a, A b, f32x16 c, int)
    -> decltype(__builtin_amdgcn_mfma_f32_32x32x16_bf16(a, b, c, 0, 0, 0)) {
    return __builtin_amdgcn_mfma_f32_32x32x16_bf16(a, b, c, 0, 0, 0);
}
template <typename A>
__device__ __forceinline__ f32x16 mfma3216_(A a, A b, f32x16 c, long) {
    b16x8 a2 = __builtin_bit_cast(b16x8, a);
    b16x8 b2 = __builtin_bit_cast(b16x8, b);
    return __builtin_amdgcn_mfma_f32_32x32x16_bf16(a2, b2, c, 0, 0, 0);
}
__device__ __forceinline__ f32x16 MFMA(u16x8 a, u16x8 b, f32x16 c) {
    return mfma3216_(__builtin_bit_cast(s16x8, a), __builtin_bit_cast(s16x8, b), c, 0);
}

// ================= P0: per-row stats (fp32, faithful to reference) =================
__global__ void __launch_bounds__(256) prep_rows(const float* __restrict__ Q,
                                                 const float* __restrict__ K,
                                                 const float* __restrict__ cp,
                                                 float* __restrict__ q2g,
                                                 float* __restrict__ k2g,
                                                 float* __restrict__ cfg) {
    const int w = threadIdx.x >> 6, l = threadIdx.x & 63;
    const float c = *cp;
#pragma unroll 1
    for (int p = 0; p < 16; ++p) {
        const int row = blockIdx.x * 64 + p * 4 + w;
        f32x4 qv = *((const f32x4*)(Q + (size_t)row * D_DIM) + l);
        f32x4 kv = *((const f32x4*)(K + (size_t)row * D_DIM) + l);
        float sq = qv[0]*qv[0] + qv[1]*qv[1] + qv[2]*qv[2] + qv[3]*qv[3];
        float sk = kv[0]*kv[0] + kv[1]*kv[1] + kv[2]*kv[2] + kv[3]*kv[3];
#pragma unroll
        for (int m = 1; m < 64; m <<= 1) {
            sq += __shfl_xor(sq, m, 64);
            sk += __shfl_xor(sk, m, 64);
        }
        if (l == 0) {
            q2g[row] = sq;
            k2g[row] = sk;
            float dn = fmaxf((1.f - c * sq) * (1.f - c * sk), 1e-6f);
            cfg[row] = 2.f * c / dn;
        }
    }
}

// ================= P1a: K -> bf16 =================
__global__ void __launch_bounds__(256) cvt_bf16(const float* __restrict__ src,
                                                unsigned short* __restrict__ dst) {
    const size_t i = ((size_t)blockIdx.x * 256 + threadIdx.x) * 8;
    f32x4 a = *(const f32x4*)(src + i);
    f32x4 b = *(const f32x4*)(src + i + 4);
    *(u16x8*)(dst + i) = pack8(a, b);
}

// ================= P1b: V -> bf16, transposed per batch: VT[b][d][j] =================
__global__ void __launch_bounds__(256) transp_v(const float* __restrict__ V,
                                                unsigned short* __restrict__ VT) {
    __shared__ float tile[64][65];
    const int bid = blockIdx.x;
    const int b = bid >> 7, rem = bid & 127, jt = rem >> 2, dt = rem & 3;
    const int j0 = jt * 64, d0 = dt * 64;
    const int t = threadIdx.x;
#pragma unroll
    for (int p = 0; p < 4; ++p) {
        const int jr = p * 16 + (t >> 4);
        f32x4 v = *(const f32x4*)(V + (size_t)(b * S_LEN + j0 + jr) * D_DIM + d0 + (t & 15) * 4);
#pragma unroll
        for (int u = 0; u < 4; ++u) tile[jr][(t & 15) * 4 + u] = v[u];
    }
    __syncthreads();
#pragma unroll
    for (int p = 0; p < 2; ++p) {
        const int dr = p * 32 + (t >> 3), seg = t & 7;
        u16x8 o;
#pragma unroll
        for (int u = 0; u < 8; ++u) o[u] = f2bf(tile[seg * 8 + u][dr]);
        *(u16x8*)(VT + (size_t)(b * D_DIM + d0 + dr) * S_LEN + j0 + seg * 8) = o;
    }
}

// ================= Main fused attention =================
// grid 256 = batch(8, ==XCD) x qtile(32, 64 q-rows). block 256 (4 waves) =
// qg(2, 32 q) x jsub(2). All 2048 j in-block: 32 iters x 64-j tiles.
// DOUBLE-BUFFERED pipeline (T3+T4): stage(buf^1,it+1) issued first, then
// s_waitcnt vmcnt(16) (prev tile landed, next 16 loads stay in flight) +
// raw s_barrier. No other VMEM in loop -> compiler emits no vmcnt(0).
// Swapped QK^T + in-register P transpose (validated r3-r6). p=y^(-1/16)<=1:
// no online max. LDS: KB 2x32KB @0 | VB 2x32KB @64K | k2sh 8K | lsum 0.5K.
template <int PRE>
__global__ void __launch_bounds__(256, 1) hyp_attn(
    const float* __restrict__ Qf, const float* __restrict__ Kf, const float* __restrict__ Vf,
    const unsigned short* __restrict__ Kb, const unsigned short* __restrict__ VTg,
    const float* __restrict__ q2g, const float* __restrict__ k2g, const float* __restrict__ cfg,
    float* __restrict__ out) {
    __shared__ __align__(1024) unsigned char tiles[131072];
    __shared__ float k2sh[S_LEN];        // 8192 B
    __shared__ float lsumBuf[2][2][32];  // 512 B    => 139776 B total

    const int bid = blockIdx.x;
    const int nb = (bid & 7) * 32 + (bid >> 3);  // batch == XCD
    const int b = nb >> 5, rt = nb & 31;
    const int tid = threadIdx.x;
    const int w = tid >> 6, l = tid & 63;
    const int l31 = l & 31, lh = l >> 5;
    const int qg = w >> 1, jsub = w & 1;
    const int qr0 = rt * 64 + qg * 32;
    const int qrow = b * S_LEN + qr0 + l31;

    // stage the batch's k2 row once (drained in prologue)
    *(f32x4*)&k2sh[tid * 8]     = *(const f32x4*)(k2g + b * S_LEN + tid * 8);
    *(f32x4*)&k2sh[tid * 8 + 4] = *(const f32x4*)(k2g + b * S_LEN + tid * 8 + 4);

    // ---- Q fragments (B-operand: col=l31, k=lh*8+j), fp32->bf16 once ----
    u16x8 qf[16];
    {
        const float* qp = Qf + (size_t)qrow * D_DIM + lh * 8;
#pragma unroll
        for (int ks = 0; ks < 16; ++ks) {
            f32x4 a = *(const f32x4*)(qp + ks * 16);
            f32x4 c4 = *(const f32x4*)(qp + ks * 16 + 4);
            qf[ks] = pack8(a, c4);
        }
    }
    const float q2r = q2g[qrow];
    const float cfr = cfg[qrow];
    const float base1 = fmaf(cfr, q2r, 1.0f);  // 1 + cf*q2

    f32x16 oacc[8];
#pragma unroll
    for (int i = 0; i < 8; ++i) oacc[i] = zero16();
    float lsum = 0.f;

    const size_t kbBase = (size_t)b * S_LEN * D_DIM;

    auto stage = [&](int buf, int it) {
        const int j0 = it * 64;
        if (PRE) {
#pragma unroll
            for (int p = 0; p < 8; ++p) {  // K: 64 rows x 32 slots(16B)
                const int idx = p * 256 + tid;
                const int row = idx >> 5, sl = idx & 31;
                const unsigned short* gp = Kb + kbBase + (size_t)(j0 + row) * D_DIM
                                         + ((sl ^ (row & 7)) << 3);
                gload16(gp, (char*)tiles + buf * 32768 + idx * 16);
            }
#pragma unroll
            for (int p = 0; p < 8; ++p) {  // VT: 256 d x 8 slots(16B)
                const int idx = p * 256 + tid;
                const int d = idx >> 3, sl = idx & 7;
                const unsigned short* gp = VTg + ((size_t)b * D_DIM + d) * S_LEN + j0
                                         + ((sl ^ (d & 7)) << 3);
                gload16(gp, (char*)tiles + 65536 + buf * 32768 + idx * 16);
            }
        } else {
#pragma unroll
            for (int p = 0; p < 8; ++p) {  // K from fp32 (reg-staged)
                const int idx = p * 256 + tid;
                const int row = idx >> 5, sl = idx & 31;
                const float* sp = Kf + kbBase + (size_t)(j0 + row) * D_DIM
                                + ((sl ^ (row & 7)) << 3);
                *(u16x8*)((char*)tiles + buf * 32768 + idx * 16) =
                    pack8(*(const f32x4*)sp, *(const f32x4*)(sp + 4));
            }
#pragma unroll
            for (int p = 0; p < 8; ++p) {  // V gather-transpose (slow fallback)
                const int idx = p * 256 + tid;
                const int d = idx >> 3, sl = idx & 7;
                const int jj = (sl ^ (d & 7)) << 3;
                u16x8 o;
#pragma unroll
                for (int u = 0; u < 8; ++u)
                    o[u] = f2bf(Vf[kbBase + (size_t)(j0 + jj + u) * D_DIM + d]);
                *(u16x8*)((char*)tiles + 65536 + buf * 32768 + idx * 16) = o;
            }
        }
    };

    const int xk = (l31 & 7) << 4;
    const char* KBp = (const char*)tiles + (jsub * 32 + l31) * 512;
    const char* VBp = (const char*)tiles + 65536 + l31 * 128;

    auto compute = [&](int buf, int it) {
        // ---- swapped QK^T: sacc[r] = S[j=jsub*32+crow(r,lh)][q=l31] ----
        f32x16 sacc = zero16();
#pragma unroll
        for (int ks = 0; ks < 16; ++ks) {
            u16x8 kf = *(const u16x8*)(KBp + buf * 32768 + (((ks * 2 + lh) << 4) ^ xk));
            sacc = MFMA(kf, qf[ks], sacc);
        }
        // ---- k2 for this wave's 32 j-rows (broadcast b128 reads) ----
        f32x4 k2q[4];
#pragma unroll
        for (int g = 0; g < 4; ++g)
            k2q[g] = *(const f32x4*)&k2sh[it * 64 + jsub * 32 + g * 8 + lh * 4];
        // ---- hyperbolic logits -> p (in place) ----
#pragma unroll
        for (int r = 0; r < 16; ++r) {
            const float t = fmaf(-2.f, sacc[r], k2q[r >> 2][r & 3]);  // k2 - 2S
            const float arg = fmaxf(fmaf(cfr, t, base1), 1.f + 1e-6f);
            const float y = arg + hw_sqrt(fmaf(arg, arg, -1.f));      // e^{arccosh}
            const float p = hw_exp2(hw_log2(y) * -0.0625f);           // y^(-1/16)
            lsum += p;
            sacc[r] = p;
        }
        // ---- in-register P transpose: lane gets A-frag rows (q=l31) ----
        unsigned A_ = cvtpk(sacc[0], sacc[1]),   C_ = cvtpk(sacc[2], sacc[3]);
        unsigned Bv = cvtpk(sacc[4], sacc[5]),   D_ = cvtpk(sacc[6], sacc[7]);
        unsigned E_ = cvtpk(sacc[8], sacc[9]),   G_ = cvtpk(sacc[10], sacc[11]);
        unsigned F_ = cvtpk(sacc[12], sacc[13]), H_ = cvtpk(sacc[14], sacc[15]);
        xswap(A_, Bv, lh); xswap(C_, D_, lh);
        xswap(E_, F_, lh); xswap(G_, H_, lh);
        const u16x8 pa0 = __builtin_bit_cast(u16x8, (u32x4){A_, C_, Bv, D_});
        const u16x8 pa1 = __builtin_bit_cast(u16x8, (u32x4){E_, G_, F_, H_});
        // ---- PV: O += P * V ----
#pragma unroll
        for (int db = 0; db < 8; ++db) {
            u16x8 vf0 = *(const u16x8*)(VBp + buf * 32768 + db * 4096 +
                                        (((jsub * 4 + lh) << 4) ^ xk));
            oacc[db] = MFMA(pa0, vf0, oacc[db]);
            u16x8 vf1 = *(const u16x8*)(VBp + buf * 32768 + db * 4096 +
                                        (((jsub * 4 + 2 + lh) << 4) ^ xk));
            oacc[db] = MFMA(pa1, vf1, oacc[db]);
        }
    };

    if (PRE) {
        // ---- pipelined: counted vmcnt keeps next tile's loads in flight ----
        stage(0, 0);
        asm volatile("s_waitcnt vmcnt(0) lgkmcnt(0)" ::: "memory");
        __builtin_amdgcn_s_barrier();
#pragma unroll 1
        for (int it = 0; it < 32; ++it) {
            const int buf = it & 1;
            if (it < 31) {
                stage(buf ^ 1, it + 1);
                asm volatile("s_waitcnt vmcnt(16)" ::: "memory");
            } else {
                asm volatile("s_waitcnt vmcnt(0)" ::: "memory");
            }
            __builtin_amdgcn_s_barrier();   // all waves' loads for buf landed
            compute(buf, it);
            __builtin_amdgcn_s_barrier();   // all reads of buf done before restage
        }
    } else {
        // ---- serial fallback (correctness-first) ----
#pragma unroll 1
        for (int it = 0; it < 32; ++it) {
            stage(0, it);
            __syncthreads();
            compute(0, it);
            __syncthreads();
        }
    }

    // ---- epilogue: combine jsub partials (2-way) ----
    __syncthreads();
    lsum += __shfl_xor(lsum, 32, 64);  // join lh halves: per-q total (this jsub)
    if (lh == 0) lsumBuf[jsub][qg][l31] = lsum;
    float* sf = (float*)tiles;  // 2 qg x 32 q x 256 d fp32 = 64KB
    if (jsub == 1) {
#pragma unroll
        for (int db = 0; db < 8; ++db)
#pragma unroll
            for (int r = 0; r < 16; ++r) {
                const int crow = (r & 3) + 8 * (r >> 2) + 4 * lh;
                sf[qg * 8192 + crow * 256 + db * 32 + l31] = oacc[db][r];
            }
    }
    __syncthreads();
    if (jsub == 0) {
        float rdn[16];
#pragma unroll
        for (int r = 0; r < 16; ++r) {
            const int crow = (r & 3) + 8 * (r >> 2) + 4 * lh;
            rdn[r] = hw_rcp(lsumBuf[0][qg][crow] + lsumBuf[1][qg][crow]);
        }
#pragma unroll
        for (int db = 0; db < 8; ++db)
#pragma unroll
            for (int r = 0; r < 16; ++r) {
                const int crow = (r & 3) + 8 * (r >> 2) + 4 * lh;
                const float o = oacc[db][r] + sf[qg * 8192 + crow * 256 + db * 32 + l31];
                out[(size_t)(b * S_LEN + qr0 + crow) * D_DIM + db * 32 + l31] = o * rdn[r];
            }
    }
}

// ================= launcher =================
extern "C" void kernel_launch(void* const* d_in, const int* in_sizes, int n_in,
                              void* d_out, int out_size, void* d_ws, size_t ws_size,
                              hipStream_t stream) {
    const float* Q = (const float*)d_in[0];
    const float* K = (const float*)d_in[1];
    const float* V = (const float*)d_in[2];
    const float* cp = (const float*)d_in[3];
    float* out = (float*)d_out;
    (void)in_sizes; (void)n_in; (void)out_size;

    const size_t BS = (size_t)B_N * S_LEN;
    float* q2g = (float*)d_ws;
    float* k2g = q2g + BS;
    float* cfg = k2g + BS;
    unsigned short* Kb = (unsigned short*)(cfg + BS);
    unsigned short* VTg = Kb + BS * D_DIM;
    const size_t need_full = 3 * BS * 4 + 2 * BS * D_DIM * 2;  // ~17 MB

    prep_rows<<<(B_N * S_LEN) / 64, 256, 0, stream>>>(Q, K, cp, q2g, k2g, cfg);

    if (ws_size >= need_full) {
        cvt_bf16<<<(int)((BS * D_DIM / 8) / 256), 256, 0, stream>>>(K, Kb);
        transp_v<<<B_N * (S_LEN / 64) * (D_DIM / 64), 256, 0, stream>>>(V, VTg);
        hyp_attn<1><<<256, 256, 0, stream>>>(Q, K, V, Kb, VTg, q2g, k2g, cfg, out);
    } else {
        hyp_attn<0><<<256, 256, 0, stream>>>(Q, K, V, Kb, VTg, q2g, k2g, cfg, out);
    }
}